// Round 12
// baseline (225.054 us; speedup 1.0000x reference)
//
#include <hip/hip_runtime.h>
#include <stdint.h>

// Problem constants (from reference):
constexpr int kB   = 8;
constexpr int kL1  = 1024;
constexpr int kC   = 128;
constexpr int kL2  = 256;
constexpr int kS   = 16;
constexpr int kNQ  = kB * kS;        // 128 queries
constexpr int kNDB = 8192;
constexpr float kEPS = 1e-8f;
constexpr int kRow = kC * kL2;       // 32768 floats per database row

constexpr int kGrid  = 256;          // persistent blocks, 1 per CU
constexpr int kGens  = kNDB / kGrid; // 32 CONSECUTIVE rows per block
constexpr int kHalfF = kRow / 2;     // 16384 floats per half tile (64 KiB)
constexpr int kNPh   = 2 * kGens;    // 64 half-row phases

// Raw barrier: LDS visibility via lgkmcnt(0), NO vmcnt drain -- global loads
// stay in flight across it (proven rounds 4-11).
#define BARRIER_LG()                                          \
    do {                                                      \
        asm volatile("s_waitcnt lgkmcnt(0)" ::: "memory");    \
        __builtin_amdgcn_s_barrier();                         \
        asm volatile("" ::: "memory");                        \
    } while (0)

// ---------------------------------------------------------------------------
// Phase 0: per-consumer gather address table, rotation baked in (proven r11).
// Consumer (q,h), h=0..3, owns l2 = h*64 + ((q&63)+g)&63, g=0..63 -- h<2 in
// l2-half 0, h>=2 in half 1. Half-tile layout [c][l2&127] (128 f/row):
//   byte offset = (c*128 + (l2&127))*4 ; bank = ((q&63)+g)&31 -> 2 lanes/bank
//   per wave instr (FREE) regardless of the data-dependent c.
// pos = f32(start) + f32(end-start)*((l2+0.5)/256) -- mul then add, NO fma.
// ---------------------------------------------------------------------------
__global__ void build_table_kernel(const int* __restrict__ seq,
                                   const int* __restrict__ kp,
                                   uint32_t* __restrict__ table) {
    __shared__ int csh[kL2];
    const int q = blockIdx.x;     // 0..127
    const int s0 = threadIdx.x;   // 0..255
    const int b = q >> 4;
    const int s = q & 15;
    int start = kp[b * (kS + 1) + s];
    int end_  = kp[b * (kS + 1) + s + 1];
    if (end_ < start + 1) end_ = start + 1;
    {
        const int l2 = s0;
        const float frac = (l2 + 0.5f) * (1.0f / 256.0f);   // exact
        const float pos = __fadd_rn((float)start,
                                    __fmul_rn((float)(end_ - start), frac));
        int idx = (int)pos;                                  // trunc, pos >= 0
        idx = idx < 0 ? 0 : (idx > kL1 - 1 ? kL1 - 1 : idx);
        csh[l2] = seq[b * kL1 + idx];
    }
    __syncthreads();
    const int h = s0 >> 6;
    const int g = s0 & 63;
    const int l2r = h * 64 + (((q & 63) + g) & 63);
    const int c = csh[l2r];
    table[(q * 4 + h) * 64 + g] = (uint32_t)((c * 128 + (l2r & 127)) * 4);
}

// ---------------------------------------------------------------------------
// Producer helpers. Half index H (row H>>1, half H&1); float4 idx f4=p+512k:
//   global = base + (H>>1)*kRow + (f4>>5)*256 + (H&1)*128 + (f4&31)*4
//   (per wave-instr: 2 contiguous 512 B runs -> coalesced)
//   LDS    = tile_half[f4*4 .. +3] (linear; 2 lanes/bank, free)
// ---------------------------------------------------------------------------
__device__ __forceinline__ void load_halfH(const float* __restrict__ base,
                                           int H, float4 (&buf)[8], int p) {
    const float* rowp = base + (size_t)(H >> 1) * kRow + (H & 1) * 128;
    #pragma unroll
    for (int k = 0; k < 8; ++k) {
        const int f4 = p + 512 * k;
        buf[k] = *reinterpret_cast<const float4*>(
            rowp + (f4 >> 5) * kL2 + (f4 & 31) * 4);
    }
}

__device__ __forceinline__ void write_half(float* tp, const float4 (&buf)[8],
                                           int p, float& nrm) {
    #pragma unroll
    for (int k = 0; k < 8; ++k) {
        const int f4 = p + 512 * k;
        const float4 v = buf[k];      // counted vmcnt wait on this reg only
        nrm = fmaf(v.x, v.x, nrm);
        nrm = fmaf(v.y, v.y, nrm);
        nrm = fmaf(v.z, v.z, nrm);
        nrm = fmaf(v.w, v.w, nrm);
        *reinterpret_cast<float4*>(tp + f4 * 4) = v;
    }
}

// ---------------------------------------------------------------------------
// Phase 1: PERSISTENT 1024-thread blocks, 1/CU, 32 consecutive rows; 64
// half-row phases; ping-pong 64 KiB tiles (structure proven r11).
// ROUND-12 CHANGE: 2-deep request pipeline. Producers hold bufA/bufB and at
// phase ph issue loads for half ph+3 (not ph+2), right after the write and
// BEFORE the norm shuffles -- two halves (128 KiB/block) of HBM requests are
// pending at all times, so the per-CU request queue never drains during the
// write/publish/barrier window (the ~14% dead window of r10/r11).
// Phase ph: consumers gather half ph from tile[ph&1]; producers write half
// ph+1 into tile[(ph+1)&1] from buf[(ph+1)&1]; reload that buffer with half
// ph+3. 1 lgkm-only barrier per phase.
// ---------------------------------------------------------------------------
__launch_bounds__(1024, 1)
__global__ void sim_kernel(const float* __restrict__ db,
                           const uint32_t* __restrict__ table,
                           float* __restrict__ sims) {
    __shared__ float tile[2][kHalfF];     // 131,072 B
    __shared__ float accp[2][4][128];     // per-(row-parity, h, q) partials
    __shared__ float nshp[2][8];          // per-(row-parity, wave) norm parts

    const int blk  = blockIdx.x;
    const int row0 = blk * kGens;
    const int t = threadIdx.x;

    if (t < 512) {
        // ================= PRODUCER =================
        const int p = t;
        const float* base = db + (size_t)row0 * kRow;
        float4 bufA[8], bufB[8];
        float nrm = 0.f;

        load_halfH(base, 0, bufA, p);     // H0 -> A
        load_halfH(base, 1, bufB, p);     // H1 -> B
        write_half(tile[0], bufA, p, nrm);            // stage H0
        load_halfH(base, 2, bufA, p);     // H2 -> A (in flight)
        BARRIER_LG();                                 // phase 0 begins

        #pragma unroll 1
        for (int ph = 0; ph < kNPh; ++ph) {
            // write half ph+1 from buf[(ph+1)&1] (vmcnt-paced = HBM pacing,
            // overlapped with consumers' gathers of half ph)
            if (ph < kNPh - 1) {
                if ((ph + 1) & 1) write_half(tile[1], bufB, p, nrm);
                else              write_half(tile[0], bufA, p, nrm);
            }

            // reload the just-drained buffer with half ph+3 (2-deep pipeline)
            if (ph + 3 < kNPh) {
                if ((ph + 3) & 1) load_halfH(base, ph + 3, bufB, p);
                else              load_halfH(base, ph + 3, bufA, p);
            }

            // even phase: half ph+1 (odd) completed row ph>>1 -> publish norm
            if ((ph & 1) == 0) {
                float nw = nrm;
                #pragma unroll
                for (int off = 32; off > 0; off >>= 1)
                    nw += __shfl_down(nw, off);
                if ((t & 63) == 0) nshp[(ph >> 1) & 1][t >> 6] = nw;
                nrm = 0.f;
            }
            BARRIER_LG();
        }
    } else {
        // ================= CONSUMER =================
        const int u = t - 512;
        const int q = u & 127;
        const int h = u >> 7;              // 0..3, wave-uniform
        float* simq = sims + (size_t)q * kNDB + row0;

        uint32_t adr[64];                  // one-time addr preload (static idx)
        {
            const uint4* tp4 = reinterpret_cast<const uint4*>(
                table + (q * 4 + h) * 64);
            #pragma unroll
            for (int g4 = 0; g4 < 16; ++g4) {
                const uint4 v = tp4[g4];
                adr[g4 * 4 + 0] = v.x;
                adr[g4 * 4 + 1] = v.y;
                adr[g4 * 4 + 2] = v.z;
                adr[g4 * 4 + 3] = v.w;
            }
        }
        BARRIER_LG();                      // match producer prologue

        #pragma unroll 1
        for (int ph = 0; ph < kNPh; ++ph) {
            // off-half h==2 waves: finalize row (ph-2)/2 (parts + norm
            // published >=1 barrier ago)
            if ((ph & 1) == 0 && h == 2 && ph >= 2) {
                const int r = (ph - 2) >> 1, pj = r & 1;
                const float total = (accp[pj][0][q] + accp[pj][1][q]) +
                                    (accp[pj][2][q] + accp[pj][3][q]);
                const float n2 =
                    ((nshp[pj][0] + nshp[pj][1]) + (nshp[pj][2] + nshp[pj][3])) +
                    ((nshp[pj][4] + nshp[pj][5]) + (nshp[pj][6] + nshp[pj][7]));
                const float inv = 1.0f / ((sqrtf(n2) + kEPS) * (16.0f + kEPS));
                simq[r] = total * inv;
            }

            // matching-half waves: 64 rotated conflict-free gathers
            if ((ph & 1) == (h >> 1)) {
                const char* tb = reinterpret_cast<const char*>(tile[ph & 1]);
                float a[8];
                #pragma unroll
                for (int i = 0; i < 8; ++i) a[i] = 0.f;
                #pragma unroll
                for (int g = 0; g < 64; ++g)
                    a[g & 7] += *reinterpret_cast<const float*>(tb + adr[g]);
                accp[(ph >> 1) & 1][h][q] =
                    ((a[0] + a[1]) + (a[2] + a[3])) +
                    ((a[4] + a[5]) + (a[6] + a[7]));
            }
            BARRIER_LG();
        }
        // tail: finalize the last row
        if (h == 2) {
            const int r = kGens - 1, pj = r & 1;
            const float total = (accp[pj][0][q] + accp[pj][1][q]) +
                                (accp[pj][2][q] + accp[pj][3][q]);
            const float n2 =
                ((nshp[pj][0] + nshp[pj][1]) + (nshp[pj][2] + nshp[pj][3])) +
                ((nshp[pj][4] + nshp[pj][5]) + (nshp[pj][6] + nshp[pj][7]));
            const float inv = 1.0f / ((sqrtf(n2) + kEPS) * (16.0f + kEPS));
            simq[r] = total * inv;
        }
    }
}

// ---------------------------------------------------------------------------
// Phase 2: per-query argmax over 8192 (first-max tie-break = lowest index),
// predictions = float(db_classes[argmax]), unit_sim = max.
// ---------------------------------------------------------------------------
__global__ void argmax_kernel(const float* __restrict__ sims,
                              const int* __restrict__ db_classes,
                              float* __restrict__ preds,
                              float* __restrict__ unit) {
    const int q = blockIdx.x;
    const int t = threadIdx.x;
    const float* row = sims + (size_t)q * kNDB;

    float best = -1e30f;
    int bidx = kNDB;
    for (int n = t; n < kNDB; n += 256) {   // increasing n: '>' keeps first max
        const float v = row[n];
        if (v > best) { best = v; bidx = n; }
    }

    __shared__ float bv[256];
    __shared__ int   bi[256];
    bv[t] = best;
    bi[t] = bidx;
    __syncthreads();
    for (int s2 = 128; s2 > 0; s2 >>= 1) {
        if (t < s2) {
            const float ov = bv[t + s2];
            const int   oi = bi[t + s2];
            if (ov > bv[t] || (ov == bv[t] && oi < bi[t])) {
                bv[t] = ov;
                bi[t] = oi;
            }
        }
        __syncthreads();
    }
    if (t == 0) {
        preds[q] = (float)db_classes[bi[0]];
        unit[q]  = bv[0];
    }
}

// ---------------------------------------------------------------------------
extern "C" void kernel_launch(void* const* d_in, const int* in_sizes, int n_in,
                              void* d_out, int out_size, void* d_ws, size_t ws_size,
                              hipStream_t stream) {
    const int*   seq        = (const int*)d_in[0];     // (8, 1024) int32
    const int*   kp         = (const int*)d_in[1];     // (8, 17)   int32
    const float* db         = (const float*)d_in[2];   // (8192, 128, 256) f32
    const int*   db_classes = (const int*)d_in[3];     // (8192,)   int32

    float* out   = (float*)d_out;                 // sims | preds | unit_sim
    float* preds = out + (size_t)kNQ * kNDB;      // + 1048576
    float* unit  = preds + kNQ;                   // + 128

    uint32_t* table = (uint32_t*)d_ws;            // 128 KiB addr table

    build_table_kernel<<<kNQ, kL2, 0, stream>>>(seq, kp, table);
    sim_kernel<<<kGrid, 1024, 0, stream>>>(db, table, out);
    argmax_kernel<<<kNQ, 256, 0, stream>>>(out, db_classes, preds, unit);
}